// Round 10
// baseline (372.008 us; speedup 1.0000x reference)
//
#include <hip/hip_runtime.h>

// GatedMoE on MI355X (gfx950), fp16 MFMA path, round 14.
// vs r13 (regressed: BM=64 doubled B-traffic + halved MFMA:barrier ratio).
// r14 = r12 + gemm2 K-SPLIT: same 128x128 tile, K=2048 split into 2x1024
// -> 960 blocks (3.75/CU, was 1.9/CU spatially starved). Partials combine
// via atomicAdd into zeroed ybuf (r12-vs-r9 measured atomics ~ neutral);
// memset(ybuf) launched first. gather unchanged. All else = r12.

typedef _Float16 half8 __attribute__((ext_vector_type(8)));
typedef _Float16 half4t __attribute__((ext_vector_type(4)));
typedef float f4 __attribute__((ext_vector_type(4)));

#define N_TOK 4096
#define DDIM  768
#define HDIM  2048
#define NEXP  8
#define CAP   614   // int(1.2 * 4096 / 8)
#define CAPP  640

// ---- workspace layout (bytes) ----
#define XH_OFF    0L           // (4097*768) fp16
#define W1T_OFF   6292992L     // [8][4096][768] fp16 (dead after gemm1)
#define YB_OFF    6292992L     // [16][640][768] fp32 ybuf (gemm2->gather), aliases w1t
#define W2T_OFF   56624640L    // [8][768][2048] fp16
#define ACT_OFF   81790464L    // [16][640][2048] fp16
#define EIDX_OFF  123733504L   // [4096][2] int
#define WTS_OFF   123766272L   // [4096][2] float
#define TOKL_OFF  123799040L   // [16][640] int
#define CNT_OFF   123840000L   // [16] int
#define INV_OFF   123840256L   // [4096][2] int (tok,k) -> z*CAPP+slot | -1

__device__ __forceinline__ void gld16(const void* g, void* l) {
  __builtin_amdgcn_global_load_lds(
      (const __attribute__((address_space(1))) unsigned int*)g,
      (__attribute__((address_space(3))) unsigned int*)l, 16, 0, 0);
}

// -------------------- wide transpose+convert: 64 rows x 128 cols --------------------
__device__ __forceinline__ void cvt2_tile(const float* __restrict__ src,
                                          _Float16* __restrict__ dst,
                                          int R, int C, int e, int r0, int c0,
                                          float* __restrict__ tile) {
  long sb = (long)e * R * C;
  int t = threadIdx.x;
  int rrow = t >> 4, c4 = (t & 15) * 4;
#pragma unroll
  for (int h = 0; h < 2; h++)
#pragma unroll
    for (int i = 0; i < 4; i++) {
      int row = i * 16 + rrow;
      f4 v = *(const f4*)(src + sb + (long)(r0 + row) * C + c0 + h * 64 + c4);
      *(f4*)(&tile[h * 4416 + row * 69 + c4]) = v;
    }
  __syncthreads();
#pragma unroll
  for (int h = 0; h < 2; h++)
#pragma unroll
    for (int s = 0; s < 2; s++) {
      int idx = t + s * 256;
      int c = idx >> 3, ch = idx & 7;
      half8 hv;
#pragma unroll
      for (int j = 0; j < 8; j++) hv[j] = (_Float16)tile[h * 4416 + (ch * 8 + j) * 69 + c];
      *(half8*)(dst + sb + (long)(c0 + h * 64 + c) * R + r0 + ch * 8) = hv;
    }
}

// -------------------- prep1: cvt_tr(W1) | router --------------------
__global__ __launch_bounds__(256) void prep1_kernel(const float* __restrict__ W1,
                                                    const float* __restrict__ x,
                                                    const float* __restrict__ Wg,
                                                    _Float16* __restrict__ w1t,
                                                    _Float16* __restrict__ xh,
                                                    int* __restrict__ eidx,
                                                    float* __restrict__ wts) {
  __shared__ float smem[2 * 4416];   // 35.3 KB: cvt tiles or wgT (24 KB)
  int b = blockIdx.x;

  if (b < 3072) {                    // ---- cvt W1
    int e = b / 384, rem = b % 384;
    int cx = rem % 12, cy = rem / 12;       // 12 r-tiles x 32 col2-tiles
    cvt2_tile(W1, w1t, 768, 4096, e, cx * 64, cy * 128, smem);
    return;
  }

  // ---- router (block-uniform path)
  int rb = b - 3072;                 // 0..1024
  int t = threadIdx.x;
  for (int i = t; i < DDIM * NEXP; i += 256) smem[(i & 7) * DDIM + (i >> 3)] = Wg[i];
  __syncthreads();
  int w = t >> 6, lane = t & 63;
  int tok = rb * 4 + w;
  if (tok > N_TOK) return;
  if (tok == N_TOK) {                // zero pad row
    half4t zz; zz[0] = zz[1] = zz[2] = zz[3] = (_Float16)0.f;
#pragma unroll
    for (int j = 0; j < 3; j++) *(half4t*)(xh + (long)N_TOK * DDIM + (lane + j * 64) * 4) = zz;
    return;
  }
  const float* xr = x + (long)tok * DDIM;
#pragma unroll
  for (int j = 0; j < 3; j++) {
    f4 v = *(const f4*)(xr + (lane + j * 64) * 4);
    half4t hv;
    hv[0] = (_Float16)v[0]; hv[1] = (_Float16)v[1];
    hv[2] = (_Float16)v[2]; hv[3] = (_Float16)v[3];
    *(half4t*)(xh + (long)tok * DDIM + (lane + j * 64) * 4) = hv;
  }
  float acc[8] = {0.f, 0.f, 0.f, 0.f, 0.f, 0.f, 0.f, 0.f};
#pragma unroll
  for (int i = 0; i < 12; i++) {
    float xv = xr[i * 64 + lane];
#pragma unroll
    for (int e2 = 0; e2 < 8; e2++) acc[e2] += xv * smem[e2 * DDIM + i * 64 + lane];
  }
#pragma unroll
  for (int e2 = 0; e2 < 8; e2++) {
    float v = acc[e2];
    v += __shfl_xor(v, 32); v += __shfl_xor(v, 16); v += __shfl_xor(v, 8);
    v += __shfl_xor(v, 4);  v += __shfl_xor(v, 2);  v += __shfl_xor(v, 1);
    acc[e2] = v;
  }
  if (lane == 0) {
    float m0 = -1e30f; int i0 = 0;
#pragma unroll
    for (int e2 = 0; e2 < 8; e2++) if (acc[e2] > m0) { m0 = acc[e2]; i0 = e2; }
    float m1 = -1e30f; int i1 = 0;
#pragma unroll
    for (int e2 = 0; e2 < 8; e2++) if (e2 != i0 && acc[e2] > m1) { m1 = acc[e2]; i1 = e2; }
    float tt = __expf(m1 - m0);
    float w0 = 1.f / (1.f + tt);
    eidx[tok * 2 + 0] = i0; eidx[tok * 2 + 1] = i1;
    wts[tok * 2 + 0] = w0;  wts[tok * 2 + 1] = 1.f - w0;
  }
}

// -------------------- capacity scan (+ inverse map) --------------------
__global__ __launch_bounds__(64) void scan_kernel(const int* __restrict__ eidx,
                                                  int* __restrict__ toklist,
                                                  int* __restrict__ counts,
                                                  int* __restrict__ inv) {
  int z = blockIdx.x;
  int k = z >> 3, e = z & 7;
  int lane = threadIdx.x;
  int mye[64];
#pragma unroll
  for (int c = 0; c < 64; c++) mye[c] = eidx[(c * 64 + lane) * 2 + k];
  int base = 0;
#pragma unroll 4
  for (int c = 0; c < 64; c++) {
    int n = c * 64 + lane;
    bool pred = (mye[c] == e);
    unsigned long long mask = __ballot(pred);
    if (pred) {
      int pos = base + __popcll(mask & ((1ull << lane) - 1ull));
      if (pos < CAP) {
        toklist[z * CAPP + pos] = n;
        inv[n * 2 + k] = z * CAPP + pos;
      } else {
        inv[n * 2 + k] = -1;              // capacity-dropped
      }
    }
    base += __popcll(mask);
  }
  if (lane == 0) counts[z] = (base < CAP) ? base : CAP;
}

// -------------------- GEMM1 + fused SwiGLU | appended cvt_tr(W2) --------------------
__global__ __launch_bounds__(256, 2) void gemm1_kernel(const _Float16* __restrict__ xh,
                                                       const _Float16* __restrict__ w1t,
                                                       const float* __restrict__ W2,
                                                       _Float16* __restrict__ w2t,
                                                       const int* __restrict__ toklist,
                                                       const int* __restrict__ counts,
                                                       _Float16* __restrict__ act) {
  __shared__ char smem[49664];   // gemm1: As 16K | Bs 32K | toks 512. cvt: 35.3K

  int i = blockIdx.x;
  if (i >= 1280) {                   // ---- cvt W2: 2048x768 per expert
    int b2 = i - 1280;               // 0..1535
    int e = b2 / 192, rem = b2 % 192;
    int cx = rem % 32, cy = rem / 32;      // 32 r-tiles x 6 col2-tiles
    cvt2_tile(W2, w2t, 2048, 768, e, cx * 64, cy * 128, (float*)smem);
    return;
  }

  _Float16* As = (_Float16*)smem;             // 128*64
  _Float16* Bs = (_Float16*)(smem + 16384);   // 256*64
  int* toks = (int*)(smem + 49152);           // 128

  int xcd = i & 7, j = i >> 3;       // 1280 blocks, 160/xcd
  int m = j % 5, ii = j / 5;
  int k = ii & 1, n = ii >> 1;
  int e = xcd, z = k * 8 + e;
  int count = counts[z];
  int m0 = m * 128;
  if (m0 >= count) return;
  int n0 = n * 128;

  int t = threadIdx.x;
  if (t < 128) {
    int r = m0 + t;
    toks[t] = (r < count) ? toklist[z * CAPP + r] : N_TOK;   // pad -> zero row
  }
  __syncthreads();

  int lane = t & 63, w = t >> 6;
  int l8 = lane >> 3, u8 = lane & 7;

  const _Float16* ag[4]; _Float16* al[4];
#pragma unroll
  for (int s = 0; s < 4; s++) {
    int row = w * 32 + s * 8 + l8;
    ag[s] = xh + (long)toks[row] * DDIM + ((u8 ^ (row & 7)) * 8);
    al[s] = As + row * 64 + u8 * 8;
  }
  const _Float16* bg[8]; _Float16* bl[8];
#pragma unroll
  for (int s = 0; s < 8; s++) {
    int rb = w * 64 + s * 8 + l8;
    int gr = (rb < 128) ? (n0 + rb) : (2048 + n0 + (rb - 128));
    bg[s] = w1t + ((long)e * 4096 + gr) * DDIM + ((u8 ^ (rb & 7)) * 8);
    bl[s] = Bs + rb * 64 + u8 * 8;
  }

  int q = lane >> 4, m16 = lane & 15;
  int wm = w & 1, wn = w >> 1;

  f4 zero4 = {0.f, 0.f, 0.f, 0.f};
  f4 acc[4][4][2];
#pragma unroll
  for (int rt = 0; rt < 4; rt++)
#pragma unroll
    for (int ct = 0; ct < 4; ct++) { acc[rt][ct][0] = zero4; acc[rt][ct][1] = zero4; }

  for (int kk = 0; kk < DDIM; kk += 64) {
    __syncthreads();
#pragma unroll
    for (int s = 0; s < 4; s++) { gld16(ag[s], al[s]); ag[s] += 64; }
#pragma unroll
    for (int s = 0; s < 8; s++) { gld16(bg[s], bl[s]); bg[s] += 64; }
    __syncthreads();

#pragma unroll
    for (int c = 0; c < 2; c++) {
      half8 af[4], bf[4][2];
#pragma unroll
      for (int rt = 0; rt < 4; rt++) {
        int row = wm * 64 + rt * 16 + m16;
        af[rt] = *(const half8*)(As + row * 64 + (((c * 4 + q) ^ (row & 7)) * 8));
      }
#pragma unroll
      for (int ct = 0; ct < 4; ct++) {
        int cb = wn * 64 + ct * 16 + m16;
        int ph = ((c * 4 + q) ^ (cb & 7)) * 8;    // (cb+128)&7 == cb&7
        bf[ct][0] = *(const half8*)(Bs + cb * 64 + ph);
        bf[ct][1] = *(const half8*)(Bs + (128 + cb) * 64 + ph);
      }
#pragma unroll
      for (int rt = 0; rt < 4; rt++)
#pragma unroll
        for (int ct = 0; ct < 4; ct++) {
          acc[rt][ct][0] = __builtin_amdgcn_mfma_f32_16x16x32_f16(af[rt], bf[ct][0], acc[rt][ct][0], 0, 0, 0);
          acc[rt][ct][1] = __builtin_amdgcn_mfma_f32_16x16x32_f16(af[rt], bf[ct][1], acc[rt][ct][1], 0, 0, 0);
        }
    }
  }

  long ab = (long)z * CAPP * HDIM;
#pragma unroll
  for (int rt = 0; rt < 4; rt++)
#pragma unroll
    for (int ct = 0; ct < 4; ct++)
#pragma unroll
      for (int r = 0; r < 4; r++) {
        int row = m0 + wm * 64 + rt * 16 + q * 4 + r;   // C/D: row = quad*4+reg
        int col = n0 + wn * 64 + ct * 16 + m16;         //      col = lane&15
        float h1 = acc[rt][ct][0][r], h2 = acc[rt][ct][1][r];
        float s = h2 / (1.f + __expf(-h2));
        act[ab + (long)row * HDIM + col] = (_Float16)(h1 * s);
      }
}

// -------------------- GEMM2 (K-split x2, 960 blocks): atomicAdd into zeroed ybuf --------------------
__global__ __launch_bounds__(256, 3) void gemm2_kernel(const _Float16* __restrict__ act,
                                                       const _Float16* __restrict__ w2t,
                                                       const int* __restrict__ counts,
                                                       float* __restrict__ ybuf) {
  int i = blockIdx.x;
  int e = i & 7, j = i >> 3;         // 960 blocks, 120/xcd
  int kh = j & 1, j2 = j >> 1;       // K-half
  int m = j2 % 5, t2 = j2 / 5;       // t2<12: k=t2&1, n=t2>>1 (0..5)
  int k = t2 & 1, n = t2 >> 1;
  int z = k * 8 + e;
  int count = counts[z];
  int m0 = m * 128;
  if (m0 >= count) return;
  int n0 = n * 128;
  int k0 = kh * 1024;

  __shared__ _Float16 As[128 * 64];   // 16 KB
  __shared__ _Float16 Bs[128 * 64];   // 16 KB

  int t = threadIdx.x;
  int lane = t & 63, w = t >> 6;
  int l8 = lane >> 3, u8 = lane & 7;

  const _Float16* ag[4]; _Float16* al[4];
#pragma unroll
  for (int s = 0; s < 4; s++) {
    int row = w * 32 + s * 8 + l8;
    ag[s] = act + ((long)z * CAPP + m0 + row) * HDIM + k0 + ((u8 ^ (row & 7)) * 8);
    al[s] = As + row * 64 + u8 * 8;
  }
  const _Float16* bg[4]; _Float16* bl[4];
#pragma unroll
  for (int s = 0; s < 4; s++) {
    int rb = w * 32 + s * 8 + l8;
    bg[s] = w2t + ((long)e * DDIM + n0 + rb) * HDIM + k0 + ((u8 ^ (rb & 7)) * 8);
    bl[s] = Bs + rb * 64 + u8 * 8;
  }

  int q = lane >> 4, m16 = lane & 15;
  int wm = w & 1, wn = w >> 1;

  f4 zero4 = {0.f, 0.f, 0.f, 0.f};
  f4 acc[4][4];
#pragma unroll
  for (int rt = 0; rt < 4; rt++)
#pragma unroll
    for (int ct = 0; ct < 4; ct++) acc[rt][ct] = zero4;

  for (int kk = 0; kk < 1024; kk += 64) {
    __syncthreads();
#pragma unroll
    for (int s = 0; s < 4; s++) { gld16(ag[s], al[s]); ag[s] += 64; }
#pragma unroll
    for (int s = 0; s < 4; s++) { gld16(bg[s], bl[s]); bg[s] += 64; }
    __syncthreads();

#pragma unroll
    for (int c = 0; c < 2; c++) {
      half8 af[4], bf[4];
#pragma unroll
      for (int rt = 0; rt < 4; rt++) {
        int row = wm * 64 + rt * 16 + m16;
        af[rt] = *(const half8*)(As + row * 64 + (((c * 4 + q) ^ (row & 7)) * 8));
      }
#pragma unroll
      for (int ct = 0; ct < 4; ct++) {
        int cb = wn * 64 + ct * 16 + m16;
        bf[ct] = *(const half8*)(Bs + cb * 64 + (((c * 4 + q) ^ (cb & 7)) * 8));
      }
#pragma unroll
      for (int rt = 0; rt < 4; rt++)
#pragma unroll
        for (int ct = 0; ct < 4; ct++)
          acc[rt][ct] = __builtin_amdgcn_mfma_f32_16x16x32_f16(af[rt], bf[ct], acc[rt][ct], 0, 0, 0);
    }
  }

  // combine K-halves: atomicAdd into zeroed ybuf (atomics measured ~neutral r9/r12)
#pragma unroll
  for (int rt = 0; rt < 4; rt++)
#pragma unroll
    for (int ct = 0; ct < 4; ct++)
#pragma unroll
      for (int r = 0; r < 4; r++) {
        int lr = wm * 64 + rt * 16 + q * 4 + r;
        int col = n0 + wn * 64 + ct * 16 + m16;
        atomicAdd(&ybuf[((long)z * CAPP + m0 + lr) * DDIM + col], acc[rt][ct][r]);
      }
}

// -------------------- gather: out[tok] = sum_k w_k * ybuf[slot_k] --------------------
__global__ __launch_bounds__(256) void gather_kernel(const float* __restrict__ ybuf,
                                                     const int* __restrict__ inv,
                                                     const float* __restrict__ wts,
                                                     float* __restrict__ out) {
  int t = threadIdx.x;
  int w = t >> 6, lane = t & 63;
  int tok = blockIdx.x * 4 + w;
  int s0 = inv[tok * 2 + 0], s1 = inv[tok * 2 + 1];
  float w0 = wts[tok * 2 + 0], w1 = wts[tok * 2 + 1];
  float acc[12];
#pragma unroll
  for (int j = 0; j < 12; j++) acc[j] = 0.f;
  int b = lane * 12;
  if (s0 >= 0) {
    const float* y = ybuf + (long)s0 * DDIM + b;
#pragma unroll
    for (int v = 0; v < 3; v++) {
      f4 qv = *(const f4*)(y + v * 4);
#pragma unroll
      for (int j = 0; j < 4; j++) acc[v * 4 + j] += w0 * qv[j];
    }
  }
  if (s1 >= 0) {
    const float* y = ybuf + (long)s1 * DDIM + b;
#pragma unroll
    for (int v = 0; v < 3; v++) {
      f4 qv = *(const f4*)(y + v * 4);
#pragma unroll
      for (int j = 0; j < 4; j++) acc[v * 4 + j] += w1 * qv[j];
    }
  }
  float* o = out + (long)tok * DDIM + b;
#pragma unroll
  for (int v = 0; v < 3; v++) {
    f4 qv;
#pragma unroll
    for (int j = 0; j < 4; j++) qv[j] = acc[v * 4 + j];
    *(f4*)(o + v * 4) = qv;
  }
}

// -------------------- launch --------------------

extern "C" void kernel_launch(void* const* d_in, const int* in_sizes, int n_in,
                              void* d_out, int out_size, void* d_ws, size_t ws_size,
                              hipStream_t stream) {
  const float* x  = (const float*)d_in[0];
  const float* Wg = (const float*)d_in[1];
  const float* W1 = (const float*)d_in[2];
  const float* W2 = (const float*)d_in[3];
  float* out = (float*)d_out;
  char* ws = (char*)d_ws;

  _Float16* xh   = (_Float16*)(ws + XH_OFF);
  _Float16* w1t  = (_Float16*)(ws + W1T_OFF);
  float*    ybuf = (float*)(ws + YB_OFF);
  _Float16* w2t  = (_Float16*)(ws + W2T_OFF);
  _Float16* actb = (_Float16*)(ws + ACT_OFF);
  int* eidx      = (int*)(ws + EIDX_OFF);
  float* wts     = (float*)(ws + WTS_OFF);
  int* toklist   = (int*)(ws + TOKL_OFF);
  int* counts    = (int*)(ws + CNT_OFF);
  int* inv       = (int*)(ws + INV_OFF);

  hipMemsetAsync(ybuf, 0, (size_t)16 * CAPP * DDIM * 4, stream);
  prep1_kernel<<<4097, 256, 0, stream>>>(W1, x, Wg, w1t, xh, eidx, wts);
  scan_kernel<<<16, 64, 0, stream>>>(eidx, toklist, counts, inv);
  gemm1_kernel<<<2816, 256, 0, stream>>>(xh, w1t, W2, w2t, toklist, counts, actb);
  gemm2_kernel<<<960, 256, 0, stream>>>(actb, w2t, counts, ybuf);
  gather_kernel<<<1024, 256, 0, stream>>>(ybuf, inv, wts, out);
}

// Round 11
// 341.248 us; speedup vs baseline: 1.0901x; 1.0901x over previous
//
#include <hip/hip_runtime.h>

// GatedMoE on MI355X (gfx950), fp16 MFMA path, round 15.
// = r12 (best, 331.3us) + ONE change: gemm1 epilogue packs the SwiGLU
// output tile through LDS (padded stride 136) and stores half8 (16B,
// 128B/16-lane group) instead of 32 scalar 2B global stores per thread.
// r13/r14 gemm2 experiments reverted (both regressed; r14 also had a
// memset-ordering aliasing hazard). gemm2 = r12 exact (plain stores,
// no atomics, no memset).

typedef _Float16 half8 __attribute__((ext_vector_type(8)));
typedef _Float16 half4t __attribute__((ext_vector_type(4)));
typedef float f4 __attribute__((ext_vector_type(4)));

#define N_TOK 4096
#define DDIM  768
#define HDIM  2048
#define NEXP  8
#define CAP   614   // int(1.2 * 4096 / 8)
#define CAPP  640

// ---- workspace layout (bytes) ----
#define XH_OFF    0L           // (4097*768) fp16
#define W1T_OFF   6292992L     // [8][4096][768] fp16 (dead after gemm1)
#define YB_OFF    6292992L     // [16][640][768] fp32 ybuf (gemm2->gather), aliases w1t
#define W2T_OFF   56624640L    // [8][768][2048] fp16
#define ACT_OFF   81790464L    // [16][640][2048] fp16
#define EIDX_OFF  123733504L   // [4096][2] int
#define WTS_OFF   123766272L   // [4096][2] float
#define TOKL_OFF  123799040L   // [16][640] int
#define CNT_OFF   123840000L   // [16] int
#define INV_OFF   123840256L   // [4096][2] int (tok,k) -> z*CAPP+slot | -1

__device__ __forceinline__ void gld16(const void* g, void* l) {
  __builtin_amdgcn_global_load_lds(
      (const __attribute__((address_space(1))) unsigned int*)g,
      (__attribute__((address_space(3))) unsigned int*)l, 16, 0, 0);
}

// -------------------- wide transpose+convert: 64 rows x 128 cols --------------------
__device__ __forceinline__ void cvt2_tile(const float* __restrict__ src,
                                          _Float16* __restrict__ dst,
                                          int R, int C, int e, int r0, int c0,
                                          float* __restrict__ tile) {
  long sb = (long)e * R * C;
  int t = threadIdx.x;
  int rrow = t >> 4, c4 = (t & 15) * 4;
#pragma unroll
  for (int h = 0; h < 2; h++)
#pragma unroll
    for (int i = 0; i < 4; i++) {
      int row = i * 16 + rrow;
      f4 v = *(const f4*)(src + sb + (long)(r0 + row) * C + c0 + h * 64 + c4);
      *(f4*)(&tile[h * 4416 + row * 69 + c4]) = v;
    }
  __syncthreads();
#pragma unroll
  for (int h = 0; h < 2; h++)
#pragma unroll
    for (int s = 0; s < 2; s++) {
      int idx = t + s * 256;
      int c = idx >> 3, ch = idx & 7;
      half8 hv;
#pragma unroll
      for (int j = 0; j < 8; j++) hv[j] = (_Float16)tile[h * 4416 + (ch * 8 + j) * 69 + c];
      *(half8*)(dst + sb + (long)(c0 + h * 64 + c) * R + r0 + ch * 8) = hv;
    }
}

// -------------------- prep1: cvt_tr(W1) | router --------------------
__global__ __launch_bounds__(256) void prep1_kernel(const float* __restrict__ W1,
                                                    const float* __restrict__ x,
                                                    const float* __restrict__ Wg,
                                                    _Float16* __restrict__ w1t,
                                                    _Float16* __restrict__ xh,
                                                    int* __restrict__ eidx,
                                                    float* __restrict__ wts) {
  __shared__ float smem[2 * 4416];   // 35.3 KB: cvt tiles or wgT (24 KB)
  int b = blockIdx.x;

  if (b < 3072) {                    // ---- cvt W1
    int e = b / 384, rem = b % 384;
    int cx = rem % 12, cy = rem / 12;       // 12 r-tiles x 32 col2-tiles
    cvt2_tile(W1, w1t, 768, 4096, e, cx * 64, cy * 128, smem);
    return;
  }

  // ---- router (block-uniform path)
  int rb = b - 3072;                 // 0..1024
  int t = threadIdx.x;
  for (int i = t; i < DDIM * NEXP; i += 256) smem[(i & 7) * DDIM + (i >> 3)] = Wg[i];
  __syncthreads();
  int w = t >> 6, lane = t & 63;
  int tok = rb * 4 + w;
  if (tok > N_TOK) return;
  if (tok == N_TOK) {                // zero pad row
    half4t zz; zz[0] = zz[1] = zz[2] = zz[3] = (_Float16)0.f;
#pragma unroll
    for (int j = 0; j < 3; j++) *(half4t*)(xh + (long)N_TOK * DDIM + (lane + j * 64) * 4) = zz;
    return;
  }
  const float* xr = x + (long)tok * DDIM;
#pragma unroll
  for (int j = 0; j < 3; j++) {
    f4 v = *(const f4*)(xr + (lane + j * 64) * 4);
    half4t hv;
    hv[0] = (_Float16)v[0]; hv[1] = (_Float16)v[1];
    hv[2] = (_Float16)v[2]; hv[3] = (_Float16)v[3];
    *(half4t*)(xh + (long)tok * DDIM + (lane + j * 64) * 4) = hv;
  }
  float acc[8] = {0.f, 0.f, 0.f, 0.f, 0.f, 0.f, 0.f, 0.f};
#pragma unroll
  for (int i = 0; i < 12; i++) {
    float xv = xr[i * 64 + lane];
#pragma unroll
    for (int e2 = 0; e2 < 8; e2++) acc[e2] += xv * smem[e2 * DDIM + i * 64 + lane];
  }
#pragma unroll
  for (int e2 = 0; e2 < 8; e2++) {
    float v = acc[e2];
    v += __shfl_xor(v, 32); v += __shfl_xor(v, 16); v += __shfl_xor(v, 8);
    v += __shfl_xor(v, 4);  v += __shfl_xor(v, 2);  v += __shfl_xor(v, 1);
    acc[e2] = v;
  }
  if (lane == 0) {
    float m0 = -1e30f; int i0 = 0;
#pragma unroll
    for (int e2 = 0; e2 < 8; e2++) if (acc[e2] > m0) { m0 = acc[e2]; i0 = e2; }
    float m1 = -1e30f; int i1 = 0;
#pragma unroll
    for (int e2 = 0; e2 < 8; e2++) if (e2 != i0 && acc[e2] > m1) { m1 = acc[e2]; i1 = e2; }
    float tt = __expf(m1 - m0);
    float w0 = 1.f / (1.f + tt);
    eidx[tok * 2 + 0] = i0; eidx[tok * 2 + 1] = i1;
    wts[tok * 2 + 0] = w0;  wts[tok * 2 + 1] = 1.f - w0;
  }
}

// -------------------- capacity scan (+ inverse map) --------------------
__global__ __launch_bounds__(64) void scan_kernel(const int* __restrict__ eidx,
                                                  int* __restrict__ toklist,
                                                  int* __restrict__ counts,
                                                  int* __restrict__ inv) {
  int z = blockIdx.x;
  int k = z >> 3, e = z & 7;
  int lane = threadIdx.x;
  int mye[64];
#pragma unroll
  for (int c = 0; c < 64; c++) mye[c] = eidx[(c * 64 + lane) * 2 + k];
  int base = 0;
#pragma unroll 4
  for (int c = 0; c < 64; c++) {
    int n = c * 64 + lane;
    bool pred = (mye[c] == e);
    unsigned long long mask = __ballot(pred);
    if (pred) {
      int pos = base + __popcll(mask & ((1ull << lane) - 1ull));
      if (pos < CAP) {
        toklist[z * CAPP + pos] = n;
        inv[n * 2 + k] = z * CAPP + pos;
      } else {
        inv[n * 2 + k] = -1;              // capacity-dropped
      }
    }
    base += __popcll(mask);
  }
  if (lane == 0) counts[z] = (base < CAP) ? base : CAP;
}

// -------------------- GEMM1 + fused SwiGLU | appended cvt_tr(W2) --------------------
__global__ __launch_bounds__(256, 2) void gemm1_kernel(const _Float16* __restrict__ xh,
                                                       const _Float16* __restrict__ w1t,
                                                       const float* __restrict__ W2,
                                                       _Float16* __restrict__ w2t,
                                                       const int* __restrict__ toklist,
                                                       const int* __restrict__ counts,
                                                       _Float16* __restrict__ act) {
  __shared__ char smem[49664];   // gemm1: As 16K | Bs 32K | toks 512. cvt: 35.3K

  int i = blockIdx.x;
  if (i >= 1280) {                   // ---- cvt W2: 2048x768 per expert
    int b2 = i - 1280;               // 0..1535
    int e = b2 / 192, rem = b2 % 192;
    int cx = rem % 32, cy = rem / 32;      // 32 r-tiles x 6 col2-tiles
    cvt2_tile(W2, w2t, 2048, 768, e, cx * 64, cy * 128, (float*)smem);
    return;
  }

  _Float16* As = (_Float16*)smem;             // 128*64
  _Float16* Bs = (_Float16*)(smem + 16384);   // 256*64
  int* toks = (int*)(smem + 49152);           // 128

  int xcd = i & 7, j = i >> 3;       // 1280 blocks, 160/xcd
  int m = j % 5, ii = j / 5;
  int k = ii & 1, n = ii >> 1;
  int e = xcd, z = k * 8 + e;
  int count = counts[z];
  int m0 = m * 128;
  if (m0 >= count) return;
  int n0 = n * 128;

  int t = threadIdx.x;
  if (t < 128) {
    int r = m0 + t;
    toks[t] = (r < count) ? toklist[z * CAPP + r] : N_TOK;   // pad -> zero row
  }
  __syncthreads();

  int lane = t & 63, w = t >> 6;
  int l8 = lane >> 3, u8 = lane & 7;

  const _Float16* ag[4]; _Float16* al[4];
#pragma unroll
  for (int s = 0; s < 4; s++) {
    int row = w * 32 + s * 8 + l8;
    ag[s] = xh + (long)toks[row] * DDIM + ((u8 ^ (row & 7)) * 8);
    al[s] = As + row * 64 + u8 * 8;
  }
  const _Float16* bg[8]; _Float16* bl[8];
#pragma unroll
  for (int s = 0; s < 8; s++) {
    int rb = w * 64 + s * 8 + l8;
    int gr = (rb < 128) ? (n0 + rb) : (2048 + n0 + (rb - 128));
    bg[s] = w1t + ((long)e * 4096 + gr) * DDIM + ((u8 ^ (rb & 7)) * 8);
    bl[s] = Bs + rb * 64 + u8 * 8;
  }

  int q = lane >> 4, m16 = lane & 15;
  int wm = w & 1, wn = w >> 1;

  f4 zero4 = {0.f, 0.f, 0.f, 0.f};
  f4 acc[4][4][2];
#pragma unroll
  for (int rt = 0; rt < 4; rt++)
#pragma unroll
    for (int ct = 0; ct < 4; ct++) { acc[rt][ct][0] = zero4; acc[rt][ct][1] = zero4; }

  for (int kk = 0; kk < DDIM; kk += 64) {
    __syncthreads();
#pragma unroll
    for (int s = 0; s < 4; s++) { gld16(ag[s], al[s]); ag[s] += 64; }
#pragma unroll
    for (int s = 0; s < 8; s++) { gld16(bg[s], bl[s]); bg[s] += 64; }
    __syncthreads();

#pragma unroll
    for (int c = 0; c < 2; c++) {
      half8 af[4], bf[4][2];
#pragma unroll
      for (int rt = 0; rt < 4; rt++) {
        int row = wm * 64 + rt * 16 + m16;
        af[rt] = *(const half8*)(As + row * 64 + (((c * 4 + q) ^ (row & 7)) * 8));
      }
#pragma unroll
      for (int ct = 0; ct < 4; ct++) {
        int cb = wn * 64 + ct * 16 + m16;
        int ph = ((c * 4 + q) ^ (cb & 7)) * 8;    // (cb+128)&7 == cb&7
        bf[ct][0] = *(const half8*)(Bs + cb * 64 + ph);
        bf[ct][1] = *(const half8*)(Bs + (128 + cb) * 64 + ph);
      }
#pragma unroll
      for (int rt = 0; rt < 4; rt++)
#pragma unroll
        for (int ct = 0; ct < 4; ct++) {
          acc[rt][ct][0] = __builtin_amdgcn_mfma_f32_16x16x32_f16(af[rt], bf[ct][0], acc[rt][ct][0], 0, 0, 0);
          acc[rt][ct][1] = __builtin_amdgcn_mfma_f32_16x16x32_f16(af[rt], bf[ct][1], acc[rt][ct][1], 0, 0, 0);
        }
    }
  }

  // epilogue: SwiGLU, then pack through LDS (stride 136) -> half8 stores
  __syncthreads();                    // all waves done reading As/Bs
  _Float16* tl = (_Float16*)smem;     // [128][136] = 34.8 KB
#pragma unroll
  for (int rt = 0; rt < 4; rt++)
#pragma unroll
    for (int ct = 0; ct < 4; ct++)
#pragma unroll
      for (int r = 0; r < 4; r++) {
        int lr = wm * 64 + rt * 16 + q * 4 + r;
        int lc = wn * 64 + ct * 16 + m16;
        float h1 = acc[rt][ct][0][r], h2 = acc[rt][ct][1][r];
        float s = h2 / (1.f + __expf(-h2));
        tl[lr * 136 + lc] = (_Float16)(h1 * s);
      }
  __syncthreads();
  long ab = (long)z * CAPP * HDIM;
  int c8 = (t & 15) * 8, rg8 = t >> 4;   // rg8 in 0..15
#pragma unroll
  for (int it = 0; it < 8; it++) {
    int row = it * 16 + rg8;
    half8 hv = *(const half8*)(tl + row * 136 + c8);
    *(half8*)(act + ab + (long)(m0 + row) * HDIM + n0 + c8) = hv;
  }
}

// -------------------- GEMM2: plain fp32 stores into ybuf (no atomics) --------------------
__global__ __launch_bounds__(256, 3) void gemm2_kernel(const _Float16* __restrict__ act,
                                                       const _Float16* __restrict__ w2t,
                                                       const int* __restrict__ counts,
                                                       float* __restrict__ ybuf) {
  int i = blockIdx.x;
  int xcd = i & 7, j = i >> 3;       // 480 blocks, 60/xcd
  int m = j % 5, t2 = j / 5;         // t2<12: k=t2&1, n=t2>>1 (0..5)
  int k = t2 & 1, n = t2 >> 1;
  int e = xcd, z = k * 8 + e;
  int count = counts[z];
  int m0 = m * 128;
  if (m0 >= count) return;
  int n0 = n * 128;

  __shared__ _Float16 As[128 * 64];   // 16 KB
  __shared__ _Float16 Bs[128 * 64];   // 16 KB

  int t = threadIdx.x;
  int lane = t & 63, w = t >> 6;
  int l8 = lane >> 3, u8 = lane & 7;

  const _Float16* ag[4]; _Float16* al[4];
#pragma unroll
  for (int s = 0; s < 4; s++) {
    int row = w * 32 + s * 8 + l8;
    ag[s] = act + ((long)z * CAPP + m0 + row) * HDIM + ((u8 ^ (row & 7)) * 8);
    al[s] = As + row * 64 + u8 * 8;
  }
  const _Float16* bg[4]; _Float16* bl[4];
#pragma unroll
  for (int s = 0; s < 4; s++) {
    int rb = w * 32 + s * 8 + l8;
    bg[s] = w2t + ((long)e * DDIM + n0 + rb) * HDIM + ((u8 ^ (rb & 7)) * 8);
    bl[s] = Bs + rb * 64 + u8 * 8;
  }

  int q = lane >> 4, m16 = lane & 15;
  int wm = w & 1, wn = w >> 1;

  f4 zero4 = {0.f, 0.f, 0.f, 0.f};
  f4 acc[4][4];
#pragma unroll
  for (int rt = 0; rt < 4; rt++)
#pragma unroll
    for (int ct = 0; ct < 4; ct++) acc[rt][ct] = zero4;

  for (int kk = 0; kk < HDIM; kk += 64) {
    __syncthreads();
#pragma unroll
    for (int s = 0; s < 4; s++) { gld16(ag[s], al[s]); ag[s] += 64; }
#pragma unroll
    for (int s = 0; s < 4; s++) { gld16(bg[s], bl[s]); bg[s] += 64; }
    __syncthreads();

#pragma unroll
    for (int c = 0; c < 2; c++) {
      half8 af[4], bf[4];
#pragma unroll
      for (int rt = 0; rt < 4; rt++) {
        int row = wm * 64 + rt * 16 + m16;
        af[rt] = *(const half8*)(As + row * 64 + (((c * 4 + q) ^ (row & 7)) * 8));
      }
#pragma unroll
      for (int ct = 0; ct < 4; ct++) {
        int cb = wn * 64 + ct * 16 + m16;
        bf[ct] = *(const half8*)(Bs + cb * 64 + (((c * 4 + q) ^ (cb & 7)) * 8));
      }
#pragma unroll
      for (int rt = 0; rt < 4; rt++)
#pragma unroll
        for (int ct = 0; ct < 4; ct++)
          acc[rt][ct] = __builtin_amdgcn_mfma_f32_16x16x32_f16(af[rt], bf[ct], acc[rt][ct], 0, 0, 0);
    }
  }

  // plain stores: ybuf[slot][col] = y (padded slots written, never gathered)
#pragma unroll
  for (int rt = 0; rt < 4; rt++)
#pragma unroll
    for (int ct = 0; ct < 4; ct++)
#pragma unroll
      for (int r = 0; r < 4; r++) {
        int lr = wm * 64 + rt * 16 + q * 4 + r;
        int col = n0 + wn * 64 + ct * 16 + m16;
        ybuf[((long)z * CAPP + m0 + lr) * DDIM + col] = acc[rt][ct][r];
      }
}

// -------------------- gather: out[tok] = sum_k w_k * ybuf[slot_k] --------------------
__global__ __launch_bounds__(256) void gather_kernel(const float* __restrict__ ybuf,
                                                     const int* __restrict__ inv,
                                                     const float* __restrict__ wts,
                                                     float* __restrict__ out) {
  int t = threadIdx.x;
  int w = t >> 6, lane = t & 63;
  int tok = blockIdx.x * 4 + w;
  int s0 = inv[tok * 2 + 0], s1 = inv[tok * 2 + 1];
  float w0 = wts[tok * 2 + 0], w1 = wts[tok * 2 + 1];
  float acc[12];
#pragma unroll
  for (int j = 0; j < 12; j++) acc[j] = 0.f;
  int b = lane * 12;
  if (s0 >= 0) {
    const float* y = ybuf + (long)s0 * DDIM + b;
#pragma unroll
    for (int v = 0; v < 3; v++) {
      f4 qv = *(const f4*)(y + v * 4);
#pragma unroll
      for (int j = 0; j < 4; j++) acc[v * 4 + j] += w0 * qv[j];
    }
  }
  if (s1 >= 0) {
    const float* y = ybuf + (long)s1 * DDIM + b;
#pragma unroll
    for (int v = 0; v < 3; v++) {
      f4 qv = *(const f4*)(y + v * 4);
#pragma unroll
      for (int j = 0; j < 4; j++) acc[v * 4 + j] += w1 * qv[j];
    }
  }
  float* o = out + (long)tok * DDIM + b;
#pragma unroll
  for (int v = 0; v < 3; v++) {
    f4 qv;
#pragma unroll
    for (int j = 0; j < 4; j++) qv[j] = acc[v * 4 + j];
    *(f4*)(o + v * 4) = qv;
  }
}

// -------------------- launch --------------------

extern "C" void kernel_launch(void* const* d_in, const int* in_sizes, int n_in,
                              void* d_out, int out_size, void* d_ws, size_t ws_size,
                              hipStream_t stream) {
  const float* x  = (const float*)d_in[0];
  const float* Wg = (const float*)d_in[1];
  const float* W1 = (const float*)d_in[2];
  const float* W2 = (const float*)d_in[3];
  float* out = (float*)d_out;
  char* ws = (char*)d_ws;

  _Float16* xh   = (_Float16*)(ws + XH_OFF);
  _Float16* w1t  = (_Float16*)(ws + W1T_OFF);
  float*    ybuf = (float*)(ws + YB_OFF);
  _Float16* w2t  = (_Float16*)(ws + W2T_OFF);
  _Float16* actb = (_Float16*)(ws + ACT_OFF);
  int* eidx      = (int*)(ws + EIDX_OFF);
  float* wts     = (float*)(ws + WTS_OFF);
  int* toklist   = (int*)(ws + TOKL_OFF);
  int* counts    = (int*)(ws + CNT_OFF);
  int* inv       = (int*)(ws + INV_OFF);

  prep1_kernel<<<4097, 256, 0, stream>>>(W1, x, Wg, w1t, xh, eidx, wts);
  scan_kernel<<<16, 64, 0, stream>>>(eidx, toklist, counts, inv);
  gemm1_kernel<<<2816, 256, 0, stream>>>(xh, w1t, W2, w2t, toklist, counts, actb);
  gemm2_kernel<<<480, 256, 0, stream>>>(actb, w2t, counts, ybuf);
  gather_kernel<<<1024, 256, 0, stream>>>(ybuf, inv, wts, out);
}

// Round 12
// 315.358 us; speedup vs baseline: 1.1796x; 1.0821x over previous
//
#include <hip/hip_runtime.h>

// GatedMoE on MI355X (gfx950), fp16 MFMA path, round 16.
// = r12 (best, 331.3us) with ONE scheduling change: prep split into
// router_kernel (1025 blocks) + scanCvt_kernel (16 scan blocks hidden
// under 3072 W1-cvt blocks). Scan previously ran ALONE (1024 threads on
// 256 CUs, ~10-15us exposed incl. cold-miss); now it overlaps the
// latency-bound cvt. Scan's prefetch reduced to an 8-deep rolling window
// so the fused kernel's VGPR stays at the cvt path's level (occupancy
// unchanged). r15's LDS-repack epilogue reverted (added 147K bank
// conflicts + 2 barriers for zero store gain - L2 already write-combines
// the scalar epilogue stores). gemm1/gemm2/gather byte-identical to r12.

typedef _Float16 half8 __attribute__((ext_vector_type(8)));
typedef _Float16 half4t __attribute__((ext_vector_type(4)));
typedef float f4 __attribute__((ext_vector_type(4)));

#define N_TOK 4096
#define DDIM  768
#define HDIM  2048
#define NEXP  8
#define CAP   614   // int(1.2 * 4096 / 8)
#define CAPP  640

// ---- workspace layout (bytes) ----
#define XH_OFF    0L           // (4097*768) fp16
#define W1T_OFF   6292992L     // [8][4096][768] fp16 (dead after gemm1)
#define YB_OFF    6292992L     // [16][640][768] fp32 ybuf (gemm2->gather), aliases w1t
#define W2T_OFF   56624640L    // [8][768][2048] fp16
#define ACT_OFF   81790464L    // [16][640][2048] fp16
#define EIDX_OFF  123733504L   // [4096][2] int
#define WTS_OFF   123766272L   // [4096][2] float
#define TOKL_OFF  123799040L   // [16][640] int
#define CNT_OFF   123840000L   // [16] int
#define INV_OFF   123840256L   // [4096][2] int (tok,k) -> z*CAPP+slot | -1

__device__ __forceinline__ void gld16(const void* g, void* l) {
  __builtin_amdgcn_global_load_lds(
      (const __attribute__((address_space(1))) unsigned int*)g,
      (__attribute__((address_space(3))) unsigned int*)l, 16, 0, 0);
}

// -------------------- wide transpose+convert: 64 rows x 128 cols --------------------
__device__ __forceinline__ void cvt2_tile(const float* __restrict__ src,
                                          _Float16* __restrict__ dst,
                                          int R, int C, int e, int r0, int c0,
                                          float* __restrict__ tile) {
  long sb = (long)e * R * C;
  int t = threadIdx.x;
  int rrow = t >> 4, c4 = (t & 15) * 4;
#pragma unroll
  for (int h = 0; h < 2; h++)
#pragma unroll
    for (int i = 0; i < 4; i++) {
      int row = i * 16 + rrow;
      f4 v = *(const f4*)(src + sb + (long)(r0 + row) * C + c0 + h * 64 + c4);
      *(f4*)(&tile[h * 4416 + row * 69 + c4]) = v;
    }
  __syncthreads();
#pragma unroll
  for (int h = 0; h < 2; h++)
#pragma unroll
    for (int s = 0; s < 2; s++) {
      int idx = t + s * 256;
      int c = idx >> 3, ch = idx & 7;
      half8 hv;
#pragma unroll
      for (int j = 0; j < 8; j++) hv[j] = (_Float16)tile[h * 4416 + (ch * 8 + j) * 69 + c];
      *(half8*)(dst + sb + (long)(c0 + h * 64 + c) * R + r0 + ch * 8) = hv;
    }
}

// -------------------- router (+ x->fp16 convert) --------------------
__global__ __launch_bounds__(256) void router_kernel(const float* __restrict__ x,
                                                     const float* __restrict__ Wg,
                                                     _Float16* __restrict__ xh,
                                                     int* __restrict__ eidx,
                                                     float* __restrict__ wts) {
  __shared__ float wgT[NEXP * DDIM];   // 24 KB transposed gate
  int t = threadIdx.x;
  for (int i = t; i < DDIM * NEXP; i += 256) wgT[(i & 7) * DDIM + (i >> 3)] = Wg[i];
  __syncthreads();
  int w = t >> 6, lane = t & 63;
  int tok = blockIdx.x * 4 + w;
  if (tok > N_TOK) return;
  if (tok == N_TOK) {                // zero pad row
    half4t zz; zz[0] = zz[1] = zz[2] = zz[3] = (_Float16)0.f;
#pragma unroll
    for (int j = 0; j < 3; j++) *(half4t*)(xh + (long)N_TOK * DDIM + (lane + j * 64) * 4) = zz;
    return;
  }
  const float* xr = x + (long)tok * DDIM;
#pragma unroll
  for (int j = 0; j < 3; j++) {
    f4 v = *(const f4*)(xr + (lane + j * 64) * 4);
    half4t hv;
    hv[0] = (_Float16)v[0]; hv[1] = (_Float16)v[1];
    hv[2] = (_Float16)v[2]; hv[3] = (_Float16)v[3];
    *(half4t*)(xh + (long)tok * DDIM + (lane + j * 64) * 4) = hv;
  }
  float acc[8] = {0.f, 0.f, 0.f, 0.f, 0.f, 0.f, 0.f, 0.f};
#pragma unroll
  for (int i = 0; i < 12; i++) {
    float xv = xr[i * 64 + lane];
#pragma unroll
    for (int e2 = 0; e2 < 8; e2++) acc[e2] += xv * wgT[e2 * DDIM + i * 64 + lane];
  }
#pragma unroll
  for (int e2 = 0; e2 < 8; e2++) {
    float v = acc[e2];
    v += __shfl_xor(v, 32); v += __shfl_xor(v, 16); v += __shfl_xor(v, 8);
    v += __shfl_xor(v, 4);  v += __shfl_xor(v, 2);  v += __shfl_xor(v, 1);
    acc[e2] = v;
  }
  if (lane == 0) {
    float m0 = -1e30f; int i0 = 0;
#pragma unroll
    for (int e2 = 0; e2 < 8; e2++) if (acc[e2] > m0) { m0 = acc[e2]; i0 = e2; }
    float m1 = -1e30f; int i1 = 0;
#pragma unroll
    for (int e2 = 0; e2 < 8; e2++) if (e2 != i0 && acc[e2] > m1) { m1 = acc[e2]; i1 = e2; }
    float tt = __expf(m1 - m0);
    float w0 = 1.f / (1.f + tt);
    eidx[tok * 2 + 0] = i0; eidx[tok * 2 + 1] = i1;
    wts[tok * 2 + 0] = w0;  wts[tok * 2 + 1] = 1.f - w0;
  }
}

// -------------------- scan (blocks 0..15, hidden) | cvt_tr(W1) (blocks 16..3087) --------------------
__global__ __launch_bounds__(256) void scanCvt_kernel(const int* __restrict__ eidx,
                                                      const float* __restrict__ W1,
                                                      int* __restrict__ toklist,
                                                      int* __restrict__ counts,
                                                      int* __restrict__ inv,
                                                      _Float16* __restrict__ w1t) {
  __shared__ float smem[2 * 4416];   // cvt tiles (35.3 KB); scan path unused
  int b = blockIdx.x;

  if (b < 16) {                      // ---- scan (one wave; 8-deep load window)
    if (threadIdx.x >= 64) return;
    int z = b;
    int k = z >> 3, e = z & 7;
    int lane = threadIdx.x;
    int pre[8];
#pragma unroll
    for (int c = 0; c < 8; c++) pre[c] = eidx[(c * 64 + lane) * 2 + k];
    int base = 0;
#pragma unroll
    for (int c = 0; c < 64; c++) {
      int my = pre[c & 7];
      if (c < 56) pre[c & 7] = eidx[((c + 8) * 64 + lane) * 2 + k];
      int n = c * 64 + lane;
      bool pred = (my == e);
      unsigned long long mask = __ballot(pred);
      if (pred) {
        int pos = base + __popcll(mask & ((1ull << lane) - 1ull));
        if (pos < CAP) {
          toklist[z * CAPP + pos] = n;
          inv[n * 2 + k] = z * CAPP + pos;
        } else {
          inv[n * 2 + k] = -1;       // capacity-dropped
        }
      }
      base += __popcll(mask);
    }
    if (lane == 0) counts[z] = (base < CAP) ? base : CAP;
    return;
  }

  // ---- cvt W1: 768x4096 per expert, 64x128 tiles
  int b2 = b - 16;                   // 0..3071
  int e = b2 / 384, rem = b2 % 384;
  int cx = rem % 12, cy = rem / 12;  // 12 r-tiles x 32 col2-tiles
  cvt2_tile(W1, w1t, 768, 4096, e, cx * 64, cy * 128, smem);
}

// -------------------- GEMM1 + fused SwiGLU | appended cvt_tr(W2) --------------------
__global__ __launch_bounds__(256, 2) void gemm1_kernel(const _Float16* __restrict__ xh,
                                                       const _Float16* __restrict__ w1t,
                                                       const float* __restrict__ W2,
                                                       _Float16* __restrict__ w2t,
                                                       const int* __restrict__ toklist,
                                                       const int* __restrict__ counts,
                                                       _Float16* __restrict__ act) {
  __shared__ char smem[49664];   // gemm1: As 16K | Bs 32K | toks 512. cvt: 35.3K

  int i = blockIdx.x;
  if (i >= 1280) {                   // ---- cvt W2: 2048x768 per expert
    int b2 = i - 1280;               // 0..1535
    int e = b2 / 192, rem = b2 % 192;
    int cx = rem % 32, cy = rem / 32;      // 32 r-tiles x 6 col2-tiles
    cvt2_tile(W2, w2t, 2048, 768, e, cx * 64, cy * 128, (float*)smem);
    return;
  }

  _Float16* As = (_Float16*)smem;             // 128*64
  _Float16* Bs = (_Float16*)(smem + 16384);   // 256*64
  int* toks = (int*)(smem + 49152);           // 128

  int xcd = i & 7, j = i >> 3;       // 1280 blocks, 160/xcd
  int m = j % 5, ii = j / 5;
  int k = ii & 1, n = ii >> 1;
  int e = xcd, z = k * 8 + e;
  int count = counts[z];
  int m0 = m * 128;
  if (m0 >= count) return;
  int n0 = n * 128;

  int t = threadIdx.x;
  if (t < 128) {
    int r = m0 + t;
    toks[t] = (r < count) ? toklist[z * CAPP + r] : N_TOK;   // pad -> zero row
  }
  __syncthreads();

  int lane = t & 63, w = t >> 6;
  int l8 = lane >> 3, u8 = lane & 7;

  const _Float16* ag[4]; _Float16* al[4];
#pragma unroll
  for (int s = 0; s < 4; s++) {
    int row = w * 32 + s * 8 + l8;
    ag[s] = xh + (long)toks[row] * DDIM + ((u8 ^ (row & 7)) * 8);
    al[s] = As + row * 64 + u8 * 8;
  }
  const _Float16* bg[8]; _Float16* bl[8];
#pragma unroll
  for (int s = 0; s < 8; s++) {
    int rb = w * 64 + s * 8 + l8;
    int gr = (rb < 128) ? (n0 + rb) : (2048 + n0 + (rb - 128));
    bg[s] = w1t + ((long)e * 4096 + gr) * DDIM + ((u8 ^ (rb & 7)) * 8);
    bl[s] = Bs + rb * 64 + u8 * 8;
  }

  int q = lane >> 4, m16 = lane & 15;
  int wm = w & 1, wn = w >> 1;

  f4 zero4 = {0.f, 0.f, 0.f, 0.f};
  f4 acc[4][4][2];
#pragma unroll
  for (int rt = 0; rt < 4; rt++)
#pragma unroll
    for (int ct = 0; ct < 4; ct++) { acc[rt][ct][0] = zero4; acc[rt][ct][1] = zero4; }

  for (int kk = 0; kk < DDIM; kk += 64) {
    __syncthreads();
#pragma unroll
    for (int s = 0; s < 4; s++) { gld16(ag[s], al[s]); ag[s] += 64; }
#pragma unroll
    for (int s = 0; s < 8; s++) { gld16(bg[s], bl[s]); bg[s] += 64; }
    __syncthreads();

#pragma unroll
    for (int c = 0; c < 2; c++) {
      half8 af[4], bf[4][2];
#pragma unroll
      for (int rt = 0; rt < 4; rt++) {
        int row = wm * 64 + rt * 16 + m16;
        af[rt] = *(const half8*)(As + row * 64 + (((c * 4 + q) ^ (row & 7)) * 8));
      }
#pragma unroll
      for (int ct = 0; ct < 4; ct++) {
        int cb = wn * 64 + ct * 16 + m16;
        int ph = ((c * 4 + q) ^ (cb & 7)) * 8;    // (cb+128)&7 == cb&7
        bf[ct][0] = *(const half8*)(Bs + cb * 64 + ph);
        bf[ct][1] = *(const half8*)(Bs + (128 + cb) * 64 + ph);
      }
#pragma unroll
      for (int rt = 0; rt < 4; rt++)
#pragma unroll
        for (int ct = 0; ct < 4; ct++) {
          acc[rt][ct][0] = __builtin_amdgcn_mfma_f32_16x16x32_f16(af[rt], bf[ct][0], acc[rt][ct][0], 0, 0, 0);
          acc[rt][ct][1] = __builtin_amdgcn_mfma_f32_16x16x32_f16(af[rt], bf[ct][1], acc[rt][ct][1], 0, 0, 0);
        }
    }
  }

  long ab = (long)z * CAPP * HDIM;
#pragma unroll
  for (int rt = 0; rt < 4; rt++)
#pragma unroll
    for (int ct = 0; ct < 4; ct++)
#pragma unroll
      for (int r = 0; r < 4; r++) {
        int row = m0 + wm * 64 + rt * 16 + q * 4 + r;   // C/D: row = quad*4+reg
        int col = n0 + wn * 64 + ct * 16 + m16;         //      col = lane&15
        float h1 = acc[rt][ct][0][r], h2 = acc[rt][ct][1][r];
        float s = h2 / (1.f + __expf(-h2));
        act[ab + (long)row * HDIM + col] = (_Float16)(h1 * s);
      }
}

// -------------------- GEMM2: plain fp32 stores into ybuf (no atomics) --------------------
__global__ __launch_bounds__(256, 3) void gemm2_kernel(const _Float16* __restrict__ act,
                                                       const _Float16* __restrict__ w2t,
                                                       const int* __restrict__ counts,
                                                       float* __restrict__ ybuf) {
  int i = blockIdx.x;
  int xcd = i & 7, j = i >> 3;       // 480 blocks, 60/xcd
  int m = j % 5, t2 = j / 5;         // t2<12: k=t2&1, n=t2>>1 (0..5)
  int k = t2 & 1, n = t2 >> 1;
  int e = xcd, z = k * 8 + e;
  int count = counts[z];
  int m0 = m * 128;
  if (m0 >= count) return;
  int n0 = n * 128;

  __shared__ _Float16 As[128 * 64];   // 16 KB
  __shared__ _Float16 Bs[128 * 64];   // 16 KB

  int t = threadIdx.x;
  int lane = t & 63, w = t >> 6;
  int l8 = lane >> 3, u8 = lane & 7;

  const _Float16* ag[4]; _Float16* al[4];
#pragma unroll
  for (int s = 0; s < 4; s++) {
    int row = w * 32 + s * 8 + l8;
    ag[s] = act + ((long)z * CAPP + m0 + row) * HDIM + ((u8 ^ (row & 7)) * 8);
    al[s] = As + row * 64 + u8 * 8;
  }
  const _Float16* bg[4]; _Float16* bl[4];
#pragma unroll
  for (int s = 0; s < 4; s++) {
    int rb = w * 32 + s * 8 + l8;
    bg[s] = w2t + ((long)e * DDIM + n0 + rb) * HDIM + ((u8 ^ (rb & 7)) * 8);
    bl[s] = Bs + rb * 64 + u8 * 8;
  }

  int q = lane >> 4, m16 = lane & 15;
  int wm = w & 1, wn = w >> 1;

  f4 zero4 = {0.f, 0.f, 0.f, 0.f};
  f4 acc[4][4];
#pragma unroll
  for (int rt = 0; rt < 4; rt++)
#pragma unroll
    for (int ct = 0; ct < 4; ct++) acc[rt][ct] = zero4;

  for (int kk = 0; kk < HDIM; kk += 64) {
    __syncthreads();
#pragma unroll
    for (int s = 0; s < 4; s++) { gld16(ag[s], al[s]); ag[s] += 64; }
#pragma unroll
    for (int s = 0; s < 4; s++) { gld16(bg[s], bl[s]); bg[s] += 64; }
    __syncthreads();

#pragma unroll
    for (int c = 0; c < 2; c++) {
      half8 af[4], bf[4];
#pragma unroll
      for (int rt = 0; rt < 4; rt++) {
        int row = wm * 64 + rt * 16 + m16;
        af[rt] = *(const half8*)(As + row * 64 + (((c * 4 + q) ^ (row & 7)) * 8));
      }
#pragma unroll
      for (int ct = 0; ct < 4; ct++) {
        int cb = wn * 64 + ct * 16 + m16;
        bf[ct] = *(const half8*)(Bs + cb * 64 + (((c * 4 + q) ^ (cb & 7)) * 8));
      }
#pragma unroll
      for (int rt = 0; rt < 4; rt++)
#pragma unroll
        for (int ct = 0; ct < 4; ct++)
          acc[rt][ct] = __builtin_amdgcn_mfma_f32_16x16x32_f16(af[rt], bf[ct], acc[rt][ct], 0, 0, 0);
    }
  }

  // plain stores: ybuf[slot][col] = y (padded slots written, never gathered)
#pragma unroll
  for (int rt = 0; rt < 4; rt++)
#pragma unroll
    for (int ct = 0; ct < 4; ct++)
#pragma unroll
      for (int r = 0; r < 4; r++) {
        int lr = wm * 64 + rt * 16 + q * 4 + r;
        int col = n0 + wn * 64 + ct * 16 + m16;
        ybuf[((long)z * CAPP + m0 + lr) * DDIM + col] = acc[rt][ct][r];
      }
}

// -------------------- gather: out[tok] = sum_k w_k * ybuf[slot_k] --------------------
__global__ __launch_bounds__(256) void gather_kernel(const float* __restrict__ ybuf,
                                                     const int* __restrict__ inv,
                                                     const float* __restrict__ wts,
                                                     float* __restrict__ out) {
  int t = threadIdx.x;
  int w = t >> 6, lane = t & 63;
  int tok = blockIdx.x * 4 + w;
  int s0 = inv[tok * 2 + 0], s1 = inv[tok * 2 + 1];
  float w0 = wts[tok * 2 + 0], w1 = wts[tok * 2 + 1];
  float acc[12];
#pragma unroll
  for (int j = 0; j < 12; j++) acc[j] = 0.f;
  int b = lane * 12;
  if (s0 >= 0) {
    const float* y = ybuf + (long)s0 * DDIM + b;
#pragma unroll
    for (int v = 0; v < 3; v++) {
      f4 qv = *(const f4*)(y + v * 4);
#pragma unroll
      for (int j = 0; j < 4; j++) acc[v * 4 + j] += w0 * qv[j];
    }
  }
  if (s1 >= 0) {
    const float* y = ybuf + (long)s1 * DDIM + b;
#pragma unroll
    for (int v = 0; v < 3; v++) {
      f4 qv = *(const f4*)(y + v * 4);
#pragma unroll
      for (int j = 0; j < 4; j++) acc[v * 4 + j] += w1 * qv[j];
    }
  }
  float* o = out + (long)tok * DDIM + b;
#pragma unroll
  for (int v = 0; v < 3; v++) {
    f4 qv;
#pragma unroll
    for (int j = 0; j < 4; j++) qv[j] = acc[v * 4 + j];
    *(f4*)(o + v * 4) = qv;
  }
}

// -------------------- launch --------------------

extern "C" void kernel_launch(void* const* d_in, const int* in_sizes, int n_in,
                              void* d_out, int out_size, void* d_ws, size_t ws_size,
                              hipStream_t stream) {
  const float* x  = (const float*)d_in[0];
  const float* Wg = (const float*)d_in[1];
  const float* W1 = (const float*)d_in[2];
  const float* W2 = (const float*)d_in[3];
  float* out = (float*)d_out;
  char* ws = (char*)d_ws;

  _Float16* xh   = (_Float16*)(ws + XH_OFF);
  _Float16* w1t  = (_Float16*)(ws + W1T_OFF);
  float*    ybuf = (float*)(ws + YB_OFF);
  _Float16* w2t  = (_Float16*)(ws + W2T_OFF);
  _Float16* actb = (_Float16*)(ws + ACT_OFF);
  int* eidx      = (int*)(ws + EIDX_OFF);
  float* wts     = (float*)(ws + WTS_OFF);
  int* toklist   = (int*)(ws + TOKL_OFF);
  int* counts    = (int*)(ws + CNT_OFF);
  int* inv       = (int*)(ws + INV_OFF);

  router_kernel<<<1025, 256, 0, stream>>>(x, Wg, xh, eidx, wts);
  scanCvt_kernel<<<3088, 256, 0, stream>>>(eidx, W1, toklist, counts, inv, w1t);
  gemm1_kernel<<<2816, 256, 0, stream>>>(xh, w1t, W2, w2t, toklist, counts, actb);
  gemm2_kernel<<<480, 256, 0, stream>>>(actb, w2t, counts, ybuf);
  gather_kernel<<<1024, 256, 0, stream>>>(ybuf, inv, wts, out);
}